// Round 2
// baseline (505.101 us; speedup 1.0000x reference)
//
#include <hip/hip_runtime.h>
#include <stdint.h>

typedef __bf16 bf16_t;
typedef __bf16 bf16x4 __attribute__((ext_vector_type(4)));
typedef __bf16 bf16x8 __attribute__((ext_vector_type(8)));
typedef float f32x16 __attribute__((ext_vector_type(16)));

#define S_LEN 4096
#define D_DIM 128
#define H_DIM 256
#define NROW 16384  // B*S

__device__ __forceinline__ f32x16 zero16() {
    f32x16 z;
#pragma unroll
    for (int i = 0; i < 16; i++) z[i] = 0.0f;
    return z;
}

__device__ __forceinline__ float silu_f(float x) {
    return x / (1.0f + __expf(-x));
}

static __device__ __forceinline__ f32x16 mfma_bf16(bf16x8 a, bf16x8 b, f32x16 c) {
    return __builtin_amdgcn_mfma_f32_32x32x16_bf16(a, b, c, 0, 0, 0);
}

// K0: cast + transpose weights to bf16 [N][K] layouts (B-operand friendly).
__global__ __launch_bounds__(256) void cast_weights_kernel(
    const float* __restrict__ Wg, const float* __restrict__ Wqk,
    const float* __restrict__ Wo,
    bf16_t* __restrict__ WgT, bf16_t* __restrict__ WqkT, bf16_t* __restrict__ WoT) {
    int idx = blockIdx.x * 256 + threadIdx.x;
    if (idx < 32768) {                       // WgT[n=256][k=128] = Wg[k][n]
        int n = idx >> 7, k = idx & 127;
        WgT[idx] = (bf16_t)Wg[k * 256 + n];
    } else if (idx < 49152) {                // WqkT[n=128][k=128]
        int j = idx - 32768;
        int n = j >> 7, k = j & 127;
        WqkT[j] = (bf16_t)Wqk[k * 128 + n];
    } else if (idx < 81920) {                // WoT[n=128][k=256] = Wo[k][n]
        int j = idx - 49152;
        int n = j >> 8, k = j & 255;
        WoT[j] = (bf16_t)Wo[k * 255 + k + n - k];  // placeholder avoided below
    }
}

// NOTE: the line above would be wrong; real implementation below re-does it.
// (kept simple: separate correct kernel)
__global__ __launch_bounds__(256) void cast_wo_kernel(
    const float* __restrict__ Wo, bf16_t* __restrict__ WoT) {
    int j = blockIdx.x * 256 + threadIdx.x;
    if (j < 32768) {
        int n = j >> 8, k = j & 255;
        WoT[j] = (bf16_t)Wo[k * 128 + n];
    }
}

// K1: rope (first 32 dims, interleaved) + layernorm in fp32 -> normed bf16;
// also cast value to bf16. One wave per row (lane l holds elems l and l+64).
__global__ __launch_bounds__(256) void rope_ln_kernel(
    const float* __restrict__ q_in, const float* __restrict__ v_in,
    const float* __restrict__ ln_g, const float* __restrict__ ln_b,
    bf16_t* __restrict__ normed, bf16_t* __restrict__ value_bf) {
    int w = threadIdx.x >> 6, l = threadIdx.x & 63;
    int row = blockIdx.x * 4 + w;
    int s = row & (S_LEN - 1);
    const float* qr = q_in + (size_t)row * D_DIM;
    float x0 = qr[l];
    float x1 = qr[l + 64];
    float partner = __shfl_xor(x0, 1, 64);
    if (l < 32) {
        int i = l >> 1;
        // inv_freq = 10000^(-i/16) = exp2(-i * log2(10000)/16)
        float f = (float)s * exp2f(-(float)i * 0.8304820237218405f);
        float sn, c;
        sincosf(f, &sn, &c);
        x0 = (l & 1) ? (x0 * c + partner * sn) : (x0 * c - partner * sn);
    }
    float sum = x0 + x1;
#pragma unroll
    for (int off = 32; off >= 1; off >>= 1) sum += __shfl_xor(sum, off, 64);
    float mu = sum * (1.0f / 128.0f);
    float d0 = x0 - mu, d1 = x1 - mu;
    float ss = d0 * d0 + d1 * d1;
#pragma unroll
    for (int off = 32; off >= 1; off >>= 1) ss += __shfl_xor(ss, off, 64);
    float rs = rsqrtf(ss * (1.0f / 128.0f) + 1e-5f);
    size_t base = (size_t)row * D_DIM;
    normed[base + l]      = (bf16_t)(d0 * rs * ln_g[l] + ln_b[l]);
    normed[base + l + 64] = (bf16_t)(d1 * rs * ln_g[l + 64] + ln_b[l + 64]);
    value_bf[base + l]      = (bf16_t)v_in[base + l];
    value_bf[base + l + 64] = (bf16_t)v_in[base + l + 64];
}

// K2: [normed;value] @ W_gate + b_gate -> silu. Blocks 0..255: gate rows
// (stored [s][h] bf16, coalesced). Blocks 256..511: v rows, transposed through
// LDS and stored vT[b][h][s] in 128-B segments (was 2-byte scattered before).
__global__ __launch_bounds__(256) void gemm_gate_v_kernel(
    const bf16_t* __restrict__ normed, const bf16_t* __restrict__ value_bf,
    const bf16_t* __restrict__ WgT, const float* __restrict__ b_gate,
    bf16_t* __restrict__ gate_bf, bf16_t* __restrict__ vT) {
    // vstage[col][row]: pitch 68 elems (136 B) -> b64 writes land 2-way max
    __shared__ __align__(16) bf16_t vstage[256 * 68];
    int w = threadIdx.x >> 6, l = threadIdx.x & 63;
    bool is_v = blockIdx.x >= 256;
    int m0 = (is_v ? (blockIdx.x - 256) : blockIdx.x) * 64;
    const bf16_t* A = is_v ? value_bf : normed;
    int rw = w >> 1, cw = w & 1;
    const bf16_t* aptr = A + (size_t)(m0 + rw * 32 + (l & 31)) * 128 + ((l >> 5) * 8);
    bf16x8 af[8];
#pragma unroll
    for (int kk = 0; kk < 8; kk++) af[kk] = *(const bf16x8*)(aptr + kk * 16);
#pragma unroll
    for (int t = 0; t < 4; t++) {
        int n0 = cw * 128 + t * 32;
        f32x16 acc = zero16();
        const bf16_t* bptr = WgT + (size_t)(n0 + (l & 31)) * 128 + ((l >> 5) * 8);
#pragma unroll
        for (int kk = 0; kk < 8; kk++) {
            bf16x8 bfv = *(const bf16x8*)(bptr + kk * 16);
            acc = mfma_bf16(af[kk], bfv, acc);
        }
        int col = n0 + (l & 31);
        float bg = b_gate[col];
        if (!is_v) {
#pragma unroll
            for (int r = 0; r < 16; r++) {
                int drow = (r & 3) + ((r >> 2) << 3) + ((l >> 5) << 2);
                int rowg = m0 + rw * 32 + drow;
                gate_bf[(size_t)rowg * 256 + col] = (bf16_t)silu_f(acc[r] + bg);
            }
        } else {
            // rows for reg group gq: base = rw*32 + 8*gq + 4*(l>>5), +q (q=0..3)
#pragma unroll
            for (int gq = 0; gq < 4; gq++) {
                int base = rw * 32 + 8 * gq + ((l >> 5) << 2);
                bf16x4 p;
#pragma unroll
                for (int q = 0; q < 4; q++) p[q] = (bf16_t)silu_f(acc[gq * 4 + q] + bg);
                *(bf16x4*)(&vstage[col * 68 + base]) = p;
            }
        }
    }
    if (is_v) {
        __syncthreads();
        // cooperative store: thread t -> sc = t&7 (8-elem s chunk), ch = t>>3
        int sc = threadIdx.x & 7, ch = threadIdx.x >> 3;
        int bb = m0 >> 12, srow = m0 & 4095;  // m0 = b*4096 + s0
#pragma unroll
        for (int it = 0; it < 8; it++) {
            int col = ch + 32 * it;
            bf16x4 lo = *(const bf16x4*)(&vstage[col * 68 + sc * 8]);
            bf16x4 hi = *(const bf16x4*)(&vstage[col * 68 + sc * 8 + 4]);
            bf16x8 o;
#pragma unroll
            for (int q = 0; q < 4; q++) { o[q] = lo[q]; o[q + 4] = hi[q]; }
            *(bf16x8*)(vT + ((size_t)bb * 256 + col) * 4096 + srow + sc * 8) = o;
        }
    }
}

// K3: qk = silu(normed @ W_qk + b_qk); q = qk*g0+b0, k = qk*g1+b1 (bf16 [s][d]).
__global__ __launch_bounds__(256) void gemm_qk_kernel(
    const bf16_t* __restrict__ normed, const bf16_t* __restrict__ WqkT,
    const float* __restrict__ b_qk, const float* __restrict__ os_gamma,
    const float* __restrict__ os_beta,
    bf16_t* __restrict__ q_ws, bf16_t* __restrict__ k_ws) {
    int w = threadIdx.x >> 6, l = threadIdx.x & 63;
    int m0 = blockIdx.x * 64;
    int rw = w >> 1, cw = w & 1;
    const bf16_t* aptr = normed + (size_t)(m0 + rw * 32 + (l & 31)) * 128 + ((l >> 5) * 8);
    bf16x8 af[8];
#pragma unroll
    for (int kk = 0; kk < 8; kk++) af[kk] = *(const bf16x8*)(aptr + kk * 16);
#pragma unroll
    for (int t = 0; t < 2; t++) {
        int n0 = cw * 64 + t * 32;
        f32x16 acc = zero16();
        const bf16_t* bptr = WqkT + (size_t)(n0 + (l & 31)) * 128 + ((l >> 5) * 8);
#pragma unroll
        for (int kk = 0; kk < 8; kk++) {
            bf16x8 bfv = *(const bf16x8*)(bptr + kk * 16);
            acc = mfma_bf16(af[kk], bfv, acc);
        }
        int col = n0 + (l & 31);
        float bq = b_qk[col];
        float g0 = os_gamma[col], g1 = os_gamma[128 + col];
        float be0 = os_beta[col], be1 = os_beta[128 + col];
#pragma unroll
        for (int r = 0; r < 16; r++) {
            int drow = (r & 3) + ((r >> 2) << 3) + ((l >> 5) << 2);
            size_t rowg = (size_t)(m0 + rw * 32 + drow);
            float sil = silu_f(acc[r] + bq);
            q_ws[rowg * 128 + col] = (bf16_t)(sil * g0 + be0);
            k_ws[rowg * 128 + col] = (bf16_t)(sil * g1 + be1);
        }
    }
}

// K4: fused attention. 1024 threads = 16 waves per block; i-tile 64, j-tile 256.
// Wave (oi, oc): sim quadrant rows oi*32, cols oc*32 (within j-tile); PV O-tile
// rows oi*32, h-slice oc*32. 16 jt iterations of 256 k-cols each.
__global__ __launch_bounds__(1024, 4) void attn_kernel(
    const bf16_t* __restrict__ q_ws, const bf16_t* __restrict__ k_ws,
    const bf16_t* __restrict__ vT, const bf16_t* __restrict__ gate_bf,
    float* __restrict__ att_map, bf16_t* __restrict__ AG) {
    int w = threadIdx.x >> 6, l = threadIdx.x & 63;
    int b = blockIdx.y;
    int i0 = blockIdx.x * 64;
    int oi = w >> 3;   // 0..1
    int oc = w & 7;    // 0..7
    __shared__ __align__(16) bf16_t attn_lds[64 * 256];  // 32 KB, xor-swizzled 16B chunks

    f32x16 O = zero16();

    const bf16_t* qptr =
        q_ws + (size_t)(b * S_LEN + i0 + oi * 32 + (l & 31)) * 128 + ((l >> 5) * 8);
    bf16x8 qf[8];
#pragma unroll
    for (int kk = 0; kk < 8; kk++) qf[kk] = *(const bf16x8*)(qptr + kk * 16);

    const float inv_S = 1.0f / 4096.0f;
    int col = oc * 32 + (l & 31);   // 0..255 within j-tile
    int cc = col >> 3;              // 0..31
    int arow = oi * 32 + (l & 31);  // PV A-row
    int rx = arow & 31;
    const bf16_t* abase = attn_lds + arow * 256;
    const bf16_t* vbase =
        vT + (size_t)(b * 256 + oc * 32 + (l & 31)) * S_LEN + ((l >> 5) * 8);

    for (int jt = 0; jt < 16; jt++) {
        int j0 = jt * 256;
        // ---- sim quadrant: rows i0+oi*32.., cols j0+oc*32.. ----
        f32x16 sacc = zero16();
        const bf16_t* kptr =
            k_ws + (size_t)(b * S_LEN + j0 + oc * 32 + (l & 31)) * 128 + ((l >> 5) * 8);
#pragma unroll
        for (int kk = 0; kk < 8; kk++) {
            bf16x8 kf = *(const bf16x8*)(kptr + kk * 16);
            sacc = mfma_bf16(qf[kk], kf, sacc);
        }
        // ---- relu^2 / S^2: nontemporal att_map store + LDS stage ----
        float* amp = att_map + (size_t)(b * S_LEN + i0 + oi * 32) * S_LEN + j0 + col;
#pragma unroll
        for (int r = 0; r < 16; r++) {
            int drow = (r & 3) + ((r >> 2) << 3) + ((l >> 5) << 2);
            int row = oi * 32 + drow;
            float v = fmaxf(sacc[r], 0.0f) * inv_S;
            float a = v * v;
            __builtin_nontemporal_store(a, amp + (size_t)drow * S_LEN);
            attn_lds[row * 256 + (((cc ^ (row & 31)) << 3) | (col & 7))] = (bf16_t)a;
        }
        __syncthreads();
        // ---- PV: O += attn(64x256) @ v(256x256), wave tile 32x32, K=256 ----
        const bf16_t* vptr = vbase + j0;
#pragma unroll
        for (int kk = 0; kk < 16; kk++) {
            bf16x8 Bf = *(const bf16x8*)(vptr + kk * 16);
            int acc_cc = kk * 2 + (l >> 5);
            bf16x8 Af = *(const bf16x8*)(abase + ((acc_cc ^ rx) << 3));
            O = mfma_bf16(Af, Bf, O);
        }
        __syncthreads();
    }
    // ---- epilogue: AG = O * gate (bf16 [s][h]) ----
    int hcol = oc * 32 + (l & 31);
#pragma unroll
    for (int r = 0; r < 16; r++) {
        int drow = (r & 3) + ((r >> 2) << 3) + ((l >> 5) << 2);
        size_t rowg = (size_t)(b * S_LEN + i0 + oi * 32 + drow);
        float g = (float)gate_bf[rowg * 256 + hcol];
        AG[rowg * 256 + hcol] = (bf16_t)(O[r] * g);
    }
}

// K5: out = AG @ W_out^T + b_out  (fp32 output, coalesced)
__global__ __launch_bounds__(256) void final_kernel(
    const bf16_t* __restrict__ AG, const bf16_t* __restrict__ WoT,
    const float* __restrict__ b_out, float* __restrict__ out) {
    int w = threadIdx.x >> 6, l = threadIdx.x & 63;
    int m0 = blockIdx.x * 64;
    int rw = w >> 1, cw = w & 1;
    const bf16_t* aptr = AG + (size_t)(m0 + rw * 32 + (l & 31)) * 256 + ((l >> 5) * 8);
    bf16x8 af[16];
#pragma unroll
    for (int kk = 0; kk < 16; kk++) af[kk] = *(const bf16x8*)(aptr + kk * 16);
#pragma unroll
    for (int t = 0; t < 2; t++) {
        int n0 = cw * 64 + t * 32;
        f32x16 acc = zero16();
        const bf16_t* bptr = WoT + (size_t)(n0 + (l & 31)) * 256 + ((l >> 5) * 8);
#pragma unroll
        for (int kk = 0; kk < 16; kk++) {
            bf16x8 bfv = *(const bf16x8*)(bptr + kk * 16);
            acc = mfma_bf16(af[kk], bfv, acc);
        }
        int col = n0 + (l & 31);
        float bo = b_out[col];
#pragma unroll
        for (int r = 0; r < 16; r++) {
            int drow = (r & 3) + ((r >> 2) << 3) + ((l >> 5) << 2);
            out[(size_t)(m0 + rw * 32 + drow) * 128 + col] = acc[r] + bo;
        }
    }
}

extern "C" void kernel_launch(void* const* d_in, const int* in_sizes, int n_in,
                              void* d_out, int out_size, void* d_ws, size_t ws_size,
                              hipStream_t stream) {
    const float* query    = (const float*)d_in[0];
    const float* value    = (const float*)d_in[2];
    const float* ln_g     = (const float*)d_in[3];
    const float* ln_b     = (const float*)d_in[4];
    const float* W_gate   = (const float*)d_in[5];
    const float* b_gate   = (const float*)d_in[6];
    const float* W_qk     = (const float*)d_in[7];
    const float* b_qk     = (const float*)d_in[8];
    const float* os_gamma = (const float*)d_in[9];
    const float* os_beta  = (const float*)d_in[10];
    const float* W_out    = (const float*)d_in[11];
    const float* b_out    = (const float*)d_in[12];

    float* out_p   = (float*)d_out;
    float* att_map = out_p + (size_t)NROW * 128;

    char* ws = (char*)d_ws;
    bf16_t* normed   = (bf16_t*)(ws);                         // 4 MB
    bf16_t* value_bf = (bf16_t*)(ws + ((size_t)4 << 20));     // 4 MB
    bf16_t* q_ws     = (bf16_t*)(ws + ((size_t)8 << 20));     // 4 MB
    bf16_t* k_ws     = (bf16_t*)(ws + ((size_t)12 << 20));    // 4 MB
    bf16_t* vT       = (bf16_t*)(ws + ((size_t)16 << 20));    // 8 MB
    bf16_t* gate_bf  = (bf16_t*)(ws + ((size_t)24 << 20));    // 8 MB
    bf16_t* AG       = (bf16_t*)(ws + ((size_t)32 << 20));    // 8 MB
    bf16_t* WgT      = (bf16_t*)(ws + ((size_t)40 << 20));    // 64 KB
    bf16_t* WqkT     = WgT + 32768;                           // 32 KB
    bf16_t* WoT      = WqkT + 16384;                          // 64 KB

    cast_weights_kernel<<<192, 256, 0, stream>>>(W_gate, W_qk, W_out, WgT, WqkT, WoT);
    cast_wo_kernel<<<128, 256, 0, stream>>>(W_out, WoT);
    rope_ln_kernel<<<4096, 256, 0, stream>>>(query, value, ln_g, ln_b, normed, value_bf);
    gemm_gate_v_kernel<<<512, 256, 0, stream>>>(normed, value_bf, WgT, b_gate, gate_bf, vT);
    gemm_qk_kernel<<<256, 256, 0, stream>>>(normed, WqkT, b_qk, os_gamma, os_beta, q_ws, k_ws);
    attn_kernel<<<dim3(64, 4), 1024, 0, stream>>>(q_ws, k_ws, vT, gate_bf, att_map, AG);
    final_kernel<<<256, 256, 0, stream>>>(AG, WoT, b_out, out_p);
}

// Round 3
// 436.984 us; speedup vs baseline: 1.1559x; 1.1559x over previous
//
#include <hip/hip_runtime.h>
#include <stdint.h>

typedef __bf16 bf16_t;
typedef __bf16 bf16x4 __attribute__((ext_vector_type(4)));
typedef __bf16 bf16x8 __attribute__((ext_vector_type(8)));
typedef float f32x16 __attribute__((ext_vector_type(16)));

#define S_LEN 4096
#define D_DIM 128
#define H_DIM 256
#define NROW 16384  // B*S

__device__ __forceinline__ f32x16 zero16() {
    f32x16 z;
#pragma unroll
    for (int i = 0; i < 16; i++) z[i] = 0.0f;
    return z;
}

__device__ __forceinline__ float silu_f(float x) {
    return x / (1.0f + __expf(-x));
}

static __device__ __forceinline__ f32x16 mfma_bf16(bf16x8 a, bf16x8 b, f32x16 c) {
    return __builtin_amdgcn_mfma_f32_32x32x16_bf16(a, b, c, 0, 0, 0);
}

// K0: cast + transpose weights to bf16 [N][K] layouts (B-operand friendly).
__global__ __launch_bounds__(256) void cast_weights_kernel(
    const float* __restrict__ Wg, const float* __restrict__ Wqk,
    const float* __restrict__ Wo,
    bf16_t* __restrict__ WgT, bf16_t* __restrict__ WqkT, bf16_t* __restrict__ WoT) {
    int idx = blockIdx.x * 256 + threadIdx.x;
    if (idx < 32768) {                       // WgT[n=256][k=128] = Wg[k][n]
        int n = idx >> 7, k = idx & 127;
        WgT[idx] = (bf16_t)Wg[k * 256 + n];
    } else if (idx < 49152) {                // WqkT[n=128][k=128]
        int j = idx - 32768;
        int n = j >> 7, k = j & 127;
        WqkT[j] = (bf16_t)Wqk[k * 128 + n];
    } else if (idx < 81920) {                // WoT[n=128][k=256] = Wo[k][n]
        int j = idx - 49152;
        int n = j >> 8, k = j & 255;
        WoT[j] = (bf16_t)Wo[k * 128 + n];
    }
}

// K1: rope (first 32 dims, interleaved) + layernorm in fp32 -> normed bf16;
// also cast value to bf16. One wave per row (lane l holds elems l and l+64).
__global__ __launch_bounds__(256) void rope_ln_kernel(
    const float* __restrict__ q_in, const float* __restrict__ v_in,
    const float* __restrict__ ln_g, const float* __restrict__ ln_b,
    bf16_t* __restrict__ normed, bf16_t* __restrict__ value_bf) {
    int w = threadIdx.x >> 6, l = threadIdx.x & 63;
    int row = blockIdx.x * 4 + w;
    int s = row & (S_LEN - 1);
    const float* qr = q_in + (size_t)row * D_DIM;
    float x0 = qr[l];
    float x1 = qr[l + 64];
    float partner = __shfl_xor(x0, 1, 64);
    if (l < 32) {
        int i = l >> 1;
        float f = (float)s * exp2f(-(float)i * 0.8304820237218405f);
        float sn, c;
        sincosf(f, &sn, &c);
        x0 = (l & 1) ? (x0 * c + partner * sn) : (x0 * c - partner * sn);
    }
    float sum = x0 + x1;
#pragma unroll
    for (int off = 32; off >= 1; off >>= 1) sum += __shfl_xor(sum, off, 64);
    float mu = sum * (1.0f / 128.0f);
    float d0 = x0 - mu, d1 = x1 - mu;
    float ss = d0 * d0 + d1 * d1;
#pragma unroll
    for (int off = 32; off >= 1; off >>= 1) ss += __shfl_xor(ss, off, 64);
    float rs = rsqrtf(ss * (1.0f / 128.0f) + 1e-5f);
    size_t base = (size_t)row * D_DIM;
    normed[base + l]      = (bf16_t)(d0 * rs * ln_g[l] + ln_b[l]);
    normed[base + l + 64] = (bf16_t)(d1 * rs * ln_g[l + 64] + ln_b[l + 64]);
    value_bf[base + l]      = (bf16_t)v_in[base + l];
    value_bf[base + l + 64] = (bf16_t)v_in[base + l + 64];
}

// K2: [normed;value] @ W_gate + b_gate -> silu. Blocks 0..255: gate rows
// (stored [s][h] bf16, coalesced). Blocks 256..511: v rows, transposed through
// LDS and emitted in MFMA B-FRAGMENT order:
//   vF frag (b, hb=h/32, j16=s/16): lane l holds v[h=hb*32+(l&31)][s=j16*16+(l>>5)*8 ..+8]
// so attn's PV B-loads are perfectly coalesced (base + lane*16B).
__global__ __launch_bounds__(256) void gemm_gate_v_kernel(
    const bf16_t* __restrict__ normed, const bf16_t* __restrict__ value_bf,
    const bf16_t* __restrict__ WgT, const float* __restrict__ b_gate,
    bf16_t* __restrict__ gate_bf, bf16_t* __restrict__ vF) {
    // vstage[col=h][row=s_local]: pitch 72 elems (144 B, 16B-aligned rows)
    __shared__ __align__(16) bf16_t vstage[256 * 72];
    int w = threadIdx.x >> 6, l = threadIdx.x & 63;
    bool is_v = blockIdx.x >= 256;
    int m0 = (is_v ? (blockIdx.x - 256) : blockIdx.x) * 64;
    const bf16_t* A = is_v ? value_bf : normed;
    int rw = w >> 1, cw = w & 1;
    const bf16_t* aptr = A + (size_t)(m0 + rw * 32 + (l & 31)) * 128 + ((l >> 5) * 8);
    bf16x8 af[8];
#pragma unroll
    for (int kk = 0; kk < 8; kk++) af[kk] = *(const bf16x8*)(aptr + kk * 16);
#pragma unroll
    for (int t = 0; t < 4; t++) {
        int n0 = cw * 128 + t * 32;
        f32x16 acc = zero16();
        const bf16_t* bptr = WgT + (size_t)(n0 + (l & 31)) * 128 + ((l >> 5) * 8);
#pragma unroll
        for (int kk = 0; kk < 8; kk++) {
            bf16x8 bfv = *(const bf16x8*)(bptr + kk * 16);
            acc = mfma_bf16(af[kk], bfv, acc);
        }
        int col = n0 + (l & 31);
        float bg = b_gate[col];
        if (!is_v) {
#pragma unroll
            for (int r = 0; r < 16; r++) {
                int drow = (r & 3) + ((r >> 2) << 3) + ((l >> 5) << 2);
                int rowg = m0 + rw * 32 + drow;
                gate_bf[(size_t)rowg * 256 + col] = (bf16_t)silu_f(acc[r] + bg);
            }
        } else {
#pragma unroll
            for (int gq = 0; gq < 4; gq++) {
                int base = rw * 32 + 8 * gq + ((l >> 5) << 2);
                bf16x4 p;
#pragma unroll
                for (int q = 0; q < 4; q++) p[q] = (bf16_t)silu_f(acc[gq * 4 + q] + bg);
                *(bf16x4*)(&vstage[col * 72 + base]) = p;
            }
        }
    }
    if (is_v) {
        __syncthreads();
        int b = m0 >> 12;
        int j16_0 = (m0 & 4095) >> 4;  // 4 consecutive j16 groups in this block
#pragma unroll
        for (int it = 0; it < 8; it++) {
            int c = threadIdx.x + 256 * it;  // 0..2047 16B-chunks
            int lane = c & 63;
            int j16l = (c >> 6) & 3;
            int hb = c >> 8;                 // 0..7
            int h = hb * 32 + (lane & 31);
            int s0 = j16l * 16 + ((lane >> 5) << 3);
            bf16x8 v = *(const bf16x8*)(&vstage[h * 72 + s0]);
            size_t fidx = ((size_t)(b * 8 + hb) * 256 + j16_0 + j16l);
            *(bf16x8*)(vF + fidx * 512 + lane * 8) = v;
        }
    }
}

// K3: qk = silu(normed @ W_qk + b_qk); q = qk*g0+b0 (bf16 [s][d]);
// k = qk*g1+b1 emitted in MFMA B-FRAGMENT order:
//   kF frag (b, jb=s/32, kk=d/16): lane l holds k[s=jb*32+(l&31)][d=kk*16+(l>>5)*8 ..+8]
__global__ __launch_bounds__(256) void gemm_qk_kernel(
    const bf16_t* __restrict__ normed, const bf16_t* __restrict__ WqkT,
    const float* __restrict__ b_qk, const float* __restrict__ os_gamma,
    const float* __restrict__ os_beta,
    bf16_t* __restrict__ q_ws, bf16_t* __restrict__ kF) {
    __shared__ __align__(16) bf16_t kstage[64 * 136];  // pitch 136 elems = 272 B
    int w = threadIdx.x >> 6, l = threadIdx.x & 63;
    int m0 = blockIdx.x * 64;
    int rw = w >> 1, cw = w & 1;
    const bf16_t* aptr = normed + (size_t)(m0 + rw * 32 + (l & 31)) * 128 + ((l >> 5) * 8);
    bf16x8 af[8];
#pragma unroll
    for (int kk = 0; kk < 8; kk++) af[kk] = *(const bf16x8*)(aptr + kk * 16);
#pragma unroll
    for (int t = 0; t < 2; t++) {
        int n0 = cw * 64 + t * 32;
        f32x16 acc = zero16();
        const bf16_t* bptr = WqkT + (size_t)(n0 + (l & 31)) * 128 + ((l >> 5) * 8);
#pragma unroll
        for (int kk = 0; kk < 8; kk++) {
            bf16x8 bfv = *(const bf16x8*)(bptr + kk * 16);
            acc = mfma_bf16(af[kk], bfv, acc);
        }
        int col = n0 + (l & 31);
        float bq = b_qk[col];
        float g0 = os_gamma[col], g1 = os_gamma[128 + col];
        float be0 = os_beta[col], be1 = os_beta[128 + col];
#pragma unroll
        for (int r = 0; r < 16; r++) {
            int drow = (r & 3) + ((r >> 2) << 3) + ((l >> 5) << 2);
            int rloc = rw * 32 + drow;
            float sil = silu_f(acc[r] + bq);
            q_ws[(size_t)(m0 + rloc) * 128 + col] = (bf16_t)(sil * g0 + be0);
            kstage[rloc * 136 + col] = (bf16_t)(sil * g1 + be1);
        }
    }
    __syncthreads();
    int b = m0 >> 12;
    int jb0 = (m0 & 4095) >> 5;  // 2 consecutive j-groups in this block
#pragma unroll
    for (int it = 0; it < 4; it++) {
        int c = threadIdx.x + 256 * it;  // 0..1023 16B-chunks
        int lane = c & 63;
        int d16 = (c >> 6) & 7;
        int jbl = c >> 9;                // 0..1
        int srow = jbl * 32 + (lane & 31);
        int d0 = d16 * 16 + ((lane >> 5) << 3);
        bf16x8 v = *(const bf16x8*)(&kstage[srow * 136 + d0]);
        size_t fidx = ((size_t)(b * 128 + jb0 + jbl) * 8 + d16);
        *(bf16x8*)(kF + fidx * 512 + lane * 8) = v;
    }
}

// K4: fused attention. 1024 threads = 16 waves; i-tile 64, j-tile 256.
// All k/v B-frag loads are coalesced from kF/vF (base + lane*16B). Only P
// goes through LDS (C-layout -> A-layout transpose, xor-swizzled 16B chunks).
__global__ __launch_bounds__(1024, 4) void attn_kernel(
    const bf16_t* __restrict__ q_ws, const bf16_t* __restrict__ kF,
    const bf16_t* __restrict__ vF, const bf16_t* __restrict__ gate_bf,
    float* __restrict__ att_map, bf16_t* __restrict__ AG) {
    int w = threadIdx.x >> 6, l = threadIdx.x & 63;
    int b = blockIdx.y;
    int i0 = blockIdx.x * 64;
    int oi = w >> 3;   // 0..1
    int oc = w & 7;    // 0..7
    __shared__ __align__(16) bf16_t attn_lds[64 * 256];  // 32 KB

    f32x16 O = zero16();

    const bf16_t* qptr =
        q_ws + (size_t)(b * S_LEN + i0 + oi * 32 + (l & 31)) * 128 + ((l >> 5) * 8);
    bf16x8 qf[8];
#pragma unroll
    for (int kk = 0; kk < 8; kk++) qf[kk] = *(const bf16x8*)(qptr + kk * 16);

    const float inv_S = 1.0f / 4096.0f;
    int col = oc * 32 + (l & 31);   // 0..255 within j-tile
    int cc = col >> 3;              // 16B-chunk id 0..31
    int arow = oi * 32 + (l & 31);  // PV A-row
    int rx = arow & 31;
    const bf16_t* abase = attn_lds + arow * 256;
    const bf16_t* kfb = kF + ((size_t)(b * 128) * 8) * 512 + l * 8;
    const bf16_t* vfb = vF + ((size_t)(b * 8 + oc) * 256) * 512 + l * 8;

    for (int jt = 0; jt < 16; jt++) {
        int j0 = jt * 256;
        // ---- sim quadrant: rows i0+oi*32.., cols j0+oc*32.. ----
        f32x16 sacc = zero16();
        const bf16_t* kp = kfb + ((size_t)(jt * 8 + oc) * 8) * 512;
#pragma unroll
        for (int kk = 0; kk < 8; kk++) {
            bf16x8 kf = *(const bf16x8*)(kp + kk * 512);
            sacc = mfma_bf16(qf[kk], kf, sacc);
        }
        // ---- relu^2 / S^2: att_map store + LDS stage ----
        float* amp = att_map + (size_t)(b * S_LEN + i0 + oi * 32) * S_LEN + j0 + col;
#pragma unroll
        for (int r = 0; r < 16; r++) {
            int drow = (r & 3) + ((r >> 2) << 3) + ((l >> 5) << 2);
            int row = oi * 32 + drow;
            float v = fmaxf(sacc[r], 0.0f) * inv_S;
            float a = v * v;
            __builtin_nontemporal_store(a, amp + (size_t)drow * S_LEN);
            attn_lds[row * 256 + (((cc ^ (row & 31)) << 3) | (col & 7))] = (bf16_t)a;
        }
        __syncthreads();
        // ---- PV: O += attn(64x256) @ v(256x256_h slice), K=256 ----
        const bf16_t* vp = vfb + (size_t)(jt * 16) * 512;
#pragma unroll
        for (int kk = 0; kk < 16; kk++) {
            bf16x8 Bf = *(const bf16x8*)(vp + kk * 512);
            int acc_cc = kk * 2 + (l >> 5);
            bf16x8 Af = *(const bf16x8*)(abase + ((acc_cc ^ rx) << 3));
            O = mfma_bf16(Af, Bf, O);
        }
        __syncthreads();
    }
    // ---- epilogue: AG = O * gate (bf16 [s][h]) ----
    int hcol = oc * 32 + (l & 31);
#pragma unroll
    for (int r = 0; r < 16; r++) {
        int drow = (r & 3) + ((r >> 2) << 3) + ((l >> 5) << 2);
        size_t rowg = (size_t)(b * S_LEN + i0 + oi * 32 + drow);
        float g = (float)gate_bf[rowg * 256 + hcol];
        AG[rowg * 256 + hcol] = (bf16_t)(O[r] * g);
    }
}

// K5: out = AG @ W_out^T + b_out  (fp32 output, coalesced)
__global__ __launch_bounds__(256) void final_kernel(
    const bf16_t* __restrict__ AG, const bf16_t* __restrict__ WoT,
    const float* __restrict__ b_out, float* __restrict__ out) {
    int w = threadIdx.x >> 6, l = threadIdx.x & 63;
    int m0 = blockIdx.x * 64;
    int rw = w >> 1, cw = w & 1;
    const bf16_t* aptr = AG + (size_t)(m0 + rw * 32 + (l & 31)) * 256 + ((l >> 5) * 8);
    bf16x8 af[16];
#pragma unroll
    for (int kk = 0; kk < 16; kk++) af[kk] = *(const bf16x8*)(aptr + kk * 16);
#pragma unroll
    for (int t = 0; t < 2; t++) {
        int n0 = cw * 64 + t * 32;
        f32x16 acc = zero16();
        const bf16_t* bptr = WoT + (size_t)(n0 + (l & 31)) * 256 + ((l >> 5) * 8);
#pragma unroll
        for (int kk = 0; kk < 16; kk++) {
            bf16x8 bfv = *(const bf16x8*)(bptr + kk * 16);
            acc = mfma_bf16(af[kk], bfv, acc);
        }
        int col = n0 + (l & 31);
        float bo = b_out[col];
#pragma unroll
        for (int r = 0; r < 16; r++) {
            int drow = (r & 3) + ((r >> 2) << 3) + ((l >> 5) << 2);
            out[(size_t)(m0 + rw * 32 + drow) * 128 + col] = acc[r] + bo;
        }
    }
}

extern "C" void kernel_launch(void* const* d_in, const int* in_sizes, int n_in,
                              void* d_out, int out_size, void* d_ws, size_t ws_size,
                              hipStream_t stream) {
    const float* query    = (const float*)d_in[0];
    const float* value    = (const float*)d_in[2];
    const float* ln_g     = (const float*)d_in[3];
    const float* ln_b     = (const float*)d_in[4];
    const float* W_gate   = (const float*)d_in[5];
    const float* b_gate   = (const float*)d_in[6];
    const float* W_qk     = (const float*)d_in[7];
    const float* b_qk     = (const float*)d_in[8];
    const float* os_gamma = (const float*)d_in[9];
    const float* os_beta  = (const float*)d_in[10];
    const float* W_out    = (const float*)d_in[11];
    const float* b_out    = (const float*)d_in[12];

    float* out_p   = (float*)d_out;
    float* att_map = out_p + (size_t)NROW * 128;

    char* ws = (char*)d_ws;
    bf16_t* normed   = (bf16_t*)(ws);                         // 4 MB
    bf16_t* value_bf = (bf16_t*)(ws + ((size_t)4 << 20));     // 4 MB
    bf16_t* q_ws     = (bf16_t*)(ws + ((size_t)8 << 20));     // 4 MB
    bf16_t* kF       = (bf16_t*)(ws + ((size_t)12 << 20));    // 4 MB
    bf16_t* vF       = (bf16_t*)(ws + ((size_t)16 << 20));    // 8 MB
    bf16_t* gate_bf  = (bf16_t*)(ws + ((size_t)24 << 20));    // 8 MB
    bf16_t* AG       = (bf16_t*)(ws + ((size_t)32 << 20));    // 8 MB
    bf16_t* WgT      = (bf16_t*)(ws + ((size_t)40 << 20));    // 64 KB
    bf16_t* WqkT     = WgT + 32768;                           // 32 KB
    bf16_t* WoT      = WqkT + 16384;                          // 64 KB

    cast_weights_kernel<<<320, 256, 0, stream>>>(W_gate, W_qk, W_out, WgT, WqkT, WoT);
    rope_ln_kernel<<<4096, 256, 0, stream>>>(query, value, ln_g, ln_b, normed, value_bf);
    gemm_gate_v_kernel<<<512, 256, 0, stream>>>(normed, value_bf, WgT, b_gate, gate_bf, vF);
    gemm_qk_kernel<<<256, 256, 0, stream>>>(normed, WqkT, b_qk, os_gamma, os_beta, q_ws, kF);
    attn_kernel<<<dim3(64, 4), 1024, 0, stream>>>(q_ws, kF, vF, gate_bf, att_map, AG);
    final_kernel<<<256, 256, 0, stream>>>(AG, WoT, b_out, out_p);
}